// Round 13
// baseline (637.585 us; speedup 1.0000x reference)
//
#include <hip/hip_runtime.h>

// MFMA pure-FP16 jet-propagation PINN.
// Jet comps: 0:val 1:x 2:y 3:t 4:xx 5:xy 6:yy 7:xt 8:yt 9:xxx 10:xxy 11:xyy 12:yyy
// J in LDS: PACKED rows m = sample*13 + comp, k = hidden neuron; f16 plane.
// Row layout: 32 chunks of 8 f16 (16 B); phys chunk = logical ^ (m&15)  (bank swizzle).
// R27 (527 us): 3 blocks/CU landed (occ 32.6) BUT spilled ~34 slots/thread
// (WRITE_SIZE 2.5KB -> 381MB/dispatch) — gain exactly cancelled. Diet missed by the
// third B buffer (P0+B1+B2 = 48 regs).
// R28: 2-BUFFER B ROTATION. P0 is dead after mfma(kb0) -> rotate loads through
// {P0,B1} only (kb1->B1, kb2->P0, ...); next-layer kb0 prefetch lands in P0 right
// after kb6 frees it (still hidden under kb7+epilogue). -16 regs; mx/mr hoisted
// out of layer() (identical all layers); 8-phase unrolled for static buffer names.
// Demand ~155 < 168 cap at launch_bounds(256,3) -> spill should vanish.
// Gate: WRITE_SIZE < 10MB. If spill persists or dur >= 520: revert to (256,2).

#define N_PTS 65536
#define HID   256
#define TS    6
#define MROWS (TS * 13)           // 78 packed rows
#define MT    5                   // M-tiles of 16 rows

typedef _Float16 half_t;
typedef __attribute__((ext_vector_type(8))) _Float16 half8;
typedef __attribute__((ext_vector_type(4))) float floatx4;

#define J_HI   0
#define REDBUF 39936              // 288 B head partials (6 samples * 4 waves * 3)
#define LDS_BYTES (REDBUF + 288)  // 40224 B -> 3 blocks/CU (120.7 KB)

struct alignas(4) hpair { half_t a, b; };

__device__ __forceinline__ float fast_tanh(float x) {
    float e = __builtin_amdgcn_exp2f(x * 2.885390081777927f);
    return 1.f - 2.f * __builtin_amdgcn_rcpf(e + 1.f);
}

__device__ __forceinline__ void tanh_jet(const float* u, float* h) {
    const float f  = fast_tanh(u[0]);
    const float f1 = 1.f - f * f;
    const float f2 = -2.f * f * f1;
    const float f3 = -2.f * f1 * f1 + 4.f * f * f * f1;
    const float ux = u[1], uy = u[2], ut = u[3];
    const float uxx = u[4], uxy = u[5], uyy = u[6], uxt = u[7], uyt = u[8];
    h[0] = f;
    h[1] = f1 * ux;  h[2] = f1 * uy;  h[3] = f1 * ut;
    h[4] = f2 * ux * ux + f1 * uxx;
    h[5] = f2 * ux * uy + f1 * uxy;
    h[6] = f2 * uy * uy + f1 * uyy;
    h[7] = f2 * ux * ut + f1 * uxt;
    h[8] = f2 * uy * ut + f1 * uyt;
    h[9]  = f3 * ux * ux * ux + 3.f * f2 * ux * uxx + f1 * u[9];
    h[10] = f3 * ux * ux * uy + f2 * (uxx * uy + 2.f * uxy * ux) + f1 * u[10];
    h[11] = f3 * ux * uy * uy + f2 * (uyy * ux + 2.f * uxy * uy) + f1 * u[11];
    h[12] = f3 * uy * uy * uy + 3.f * f2 * uy * uyy + f1 * u[12];
}

// ---- prep: split W2, W3, Wp1, Wd1 into f16 hi/lo planes, FRAGMENT-ORDERED ----
// (lo plane unused by the main kernel; kept for layout compatibility)
__global__ void prep_w(const float* __restrict__ W2, const float* __restrict__ W3,
                       const float* __restrict__ Wp1, const float* __restrict__ Wd1,
                       half_t* __restrict__ ws) {
    int idx = blockIdx.x * 256 + threadIdx.x;
#pragma unroll
    for (int r = 0; r < 4; ++r) {
        int e = idx + r * 65536;
        int m = e >> 16, i = e & 65535;
        const float* src = (m == 0) ? W2 : (m == 1) ? W3 : (m == 2) ? Wp1 : Wd1;
        float w = src[i];
        half_t hi = (half_t)w;
        half_t lo = (half_t)(w - (float)hi);
        int n = i >> 8, k = i & 255;
        int addr = (((n >> 4) * 8 + (k >> 5)) * 64 + ((k >> 3) & 3) * 16 + (n & 15)) * 8
                   + (k & 7);
        ws[m * 131072 + addr] = hi;
        ws[m * 131072 + 65536 + addr] = lo;
    }
}

// coalesced fragment load, SCALAR base: bh is wave-uniform (readfirstlane),
// vo = lane*8 halfs is the only per-lane term -> SGPR-base global_load.
__device__ __forceinline__ void load_B(const half_t* bh, int vo, int kb,
                                       half8 (&Bh)[4]) {
#pragma unroll
    for (int nt = 0; nt < 4; ++nt) {
        int off = nt * 4096 + kb * 512 + vo;   // halfs; nt,kb uniform
        Bh[nt] = *(const half8*)(bh + off);
    }
}

// one kb step: MT A-tiles (precomputed row bases, xor-folded chunk), 20 MFMAs.
__device__ __forceinline__ void mfma_phase(const char* __restrict__ smem,
                                           const int (&mx)[MT], const int (&mr)[MT],
                                           int kb, int q,
                                           const half8 (&Bh)[4],
                                           floatx4 (&acc)[MT][4]) {
    const int kq = (kb * 4 + q) << 4;
    __builtin_amdgcn_s_setprio(1);
#pragma unroll
    for (int mt = 0; mt < MT; ++mt) {
        const int a = mr[mt] + (kq ^ mx[mt]);
        half8 Ah = *(const half8*)(smem + J_HI + a);
#pragma unroll
        for (int nt = 0; nt < 4; ++nt) {
            acc[mt][nt] = __builtin_amdgcn_mfma_f32_16x16x32_f16(Ah, Bh[nt], acc[mt][nt], 0, 0, 0);
        }
    }
    __builtin_amdgcn_s_setprio(0);
}

// ROLLING post-barrier epilogue: per tile, transpose (dual-writeback permlane) into
// ccur[16]; jet every sample completing at this tile (rows span cprev|ccur); store
// f16 to J. Peak live: acc (freeing) + 32 window + 26 jet temps.
__device__ __forceinline__ void epilogue_roll(char* __restrict__ smem,
                                              const float* __restrict__ bias,
                                              int wave, int lane,
                                              floatx4 (&acc)[MT][4]) {
    const int n = wave * 64 + lane;
    const float bn = bias[n];
    const int lanebase = ((n >> 3) << 4) | ((n & 7) << 1);
    float cprev[16], ccur[16];
    // samples completing at tile mt: {0},{1},{2},{3},{4,5}
    const int s_lo[MT] = {0, 1, 2, 3, 4};
    const int s_hi[MT] = {0, 1, 2, 3, 5};
#pragma unroll
    for (int mt = 0; mt < MT; ++mt) {
        float tv[4][4];
#pragma unroll
        for (int j = 0; j < 4; ++j)
#pragma unroll
            for (int r = 0; r < 4; ++r) tv[j][r] = acc[mt][j][r];
#pragma unroll
        for (int r = 0; r < 4; ++r) {
            asm("v_permlane16_swap_b32 %0, %1" : "+v"(tv[0][r]), "+v"(tv[1][r]));
            asm("v_permlane16_swap_b32 %0, %1" : "+v"(tv[2][r]), "+v"(tv[3][r]));
            asm("v_permlane32_swap_b32 %0, %1" : "+v"(tv[0][r]), "+v"(tv[2][r]));
            asm("v_permlane32_swap_b32 %0, %1" : "+v"(tv[1][r]), "+v"(tv[3][r]));
        }
#pragma unroll
        for (int j = 0; j < 4; ++j)
#pragma unroll
            for (int r = 0; r < 4; ++r) ccur[j * 4 + r] = tv[j][r];
#pragma unroll
        for (int s = s_lo[mt]; s <= s_hi[mt]; ++s) {
            float u[13], h[13];
#pragma unroll
            for (int c = 0; c < 13; ++c) {
                const int row = 13 * s + c;           // tile row>>4 == mt or mt-1
                u[c] = ((row >> 4) == mt) ? ccur[row & 15] : cprev[row & 15];
            }
            u[0] += bn;
            tanh_jet(u, h);
#pragma unroll
            for (int c = 0; c < 13; ++c) {
                const int m = 13 * s + c;
                const int off = m * 512 + (lanebase ^ ((m & 15) << 4));
                *(half_t*)(smem + J_HI + off) = (half_t)h[c];
            }
        }
#pragma unroll
        for (int i = 0; i < 16; ++i) cprev[i] = ccur[i];
    }
}

// one full layer, 2-BUFFER ROTATION: kb even -> P0, kb odd -> B1; load kb+1 while
// computing kb; next-layer kb0 prefetch lands in P0 right after kb6 frees it.
__device__ __forceinline__ void layer(char* __restrict__ smem,
                                      const half_t* bh,
                                      const float* __restrict__ bias,
                                      int wave, int lane, int vo, int q,
                                      const int (&mx)[MT], const int (&mr)[MT],
                                      const half_t* nbh,
                                      half8 (&P0)[4],
                                      floatx4 (&acc)[MT][4]) {
    half8 B1[4];
    load_B(bh, vo, 1, B1);
#pragma unroll
    for (int mt = 0; mt < MT; ++mt)
#pragma unroll
        for (int nt = 0; nt < 4; ++nt) acc[mt][nt] = floatx4{0.f, 0.f, 0.f, 0.f};
    mfma_phase(smem, mx, mr, 0, q, P0, acc);   // P0 now free
    load_B(bh, vo, 2, P0);
    mfma_phase(smem, mx, mr, 1, q, B1, acc);
    load_B(bh, vo, 3, B1);
    mfma_phase(smem, mx, mr, 2, q, P0, acc);
    load_B(bh, vo, 4, P0);
    mfma_phase(smem, mx, mr, 3, q, B1, acc);
    load_B(bh, vo, 5, B1);
    mfma_phase(smem, mx, mr, 4, q, P0, acc);
    load_B(bh, vo, 6, P0);
    mfma_phase(smem, mx, mr, 5, q, B1, acc);
    load_B(bh, vo, 7, B1);
    mfma_phase(smem, mx, mr, 6, q, P0, acc);   // P0 free again
    load_B(nbh, vo, 0, P0);                    // prefetch next layer kb0
    mfma_phase(smem, mx, mr, 7, q, B1, acc);
    __syncthreads();                 // all waves' J reads done before overwrite
    epilogue_roll(smem, bias, wave, lane, acc);
    __syncthreads();                 // publish new J
}

// head kb step: 2 tiles, 8 MFMAs
__device__ __forceinline__ void head_phase(const char* __restrict__ smem,
                                           const int (&mh)[2], int kb, int q,
                                           const half8 (&Bh)[4],
                                           floatx4 (&hacc)[2][4]) {
    __builtin_amdgcn_s_setprio(1);
#pragma unroll
    for (int ht = 0; ht < 2; ++ht) {
        const int a = mh[ht] * 512 + ((((kb * 4 + q) << 4)) ^ ((mh[ht] & 15) << 4));
        half8 Ah = *(const half8*)(smem + J_HI + a);
#pragma unroll
        for (int nt = 0; nt < 4; ++nt) {
            hacc[ht][nt] = __builtin_amdgcn_mfma_f32_16x16x32_f16(Ah, Bh[nt], hacc[ht][nt], 0, 0, 0);
        }
    }
    __builtin_amdgcn_s_setprio(0);
}

__global__ __launch_bounds__(256, 3) void pinn_mfma(
    const float* __restrict__ gx, const float* __restrict__ gy, const float* __restrict__ gt,
    const float* __restrict__ W1, const float* __restrict__ b1,
    const float* __restrict__ b2, const float* __restrict__ b3,
    const float* __restrict__ bp1, const float* __restrict__ Wp2,
    const float* __restrict__ bd1, const float* __restrict__ Wd2,
    const float* __restrict__ bd2,
    const float* __restrict__ lam1p, const float* __restrict__ lam2p,
    const half_t* __restrict__ wsw, float* __restrict__ out) {
    extern __shared__ char smem[];
    const int t = threadIdx.x;
    const int wave = t >> 6, lane = t & 63;
    const int q = lane >> 4, nl = lane & 15;
    const int base = blockIdx.x * TS;
    // wave-uniform B base offset (halfs) + per-lane offset: scalarized addressing
    const int wo = __builtin_amdgcn_readfirstlane(wave) * 16384;
    const int vo = lane * 8;

    const half_t* W2h = wsw + wo;
    const half_t* W3h = wsw + 131072 + wo;
    const half_t* Wph = wsw + 2 * 131072 + wo;
    const half_t* Wdh = wsw + 3 * 131072 + wo;

    // A-row bases identical for every layer: compute once
    int mx[MT], mr[MT];
#pragma unroll
    for (int mt = 0; mt < MT; ++mt) {
        int m = mt * 16 + nl;
        if (m > MROWS - 1) m = MROWS - 1;   // tile 4 clamp (C rows 78/79 discarded)
        mx[mt] = (m & 15) << 4;
        mr[mt] = m * 512;
    }

    // persistent kb0 buffer: W2's kb0 load hides under the prologue
    half8 P0[4];
    load_B(W2h, vo, 0, P0);

    // ---------------- Layer 1: (x,y,t) -> J1 ----------------
#pragma unroll 1
    for (int ii = 0; ii < 3; ++ii) {
        int p = ii * 256 + t;               // (sample, j-pair) 0..TS*128-1 (=768 exact)
        int s = p >> 7, j = (p & 127) * 2;
        int gi = base + s; if (gi >= N_PTS) gi = N_PTS - 1;   // tail clamp
        float qx = gx[gi], qy = gy[gi], qt = gt[gi];
        float hv[2][13];
#pragma unroll
        for (int d = 0; d < 2; ++d) {
            int jj = j + d;
            float w0 = W1[3 * jj], w1 = W1[3 * jj + 1], w2 = W1[3 * jj + 2];
            float f = fast_tanh(w0 * qx + w1 * qy + w2 * qt + b1[jj]);
            float f1 = 1.f - f * f;
            float f2c = -2.f * f * f1;
            float f3c = -2.f * f1 * f1 + 4.f * f * f * f1;
            float* h = hv[d];
            h[0] = f; h[1] = f1 * w0; h[2] = f1 * w1; h[3] = f1 * w2;
            h[4] = f2c * w0 * w0; h[5] = f2c * w0 * w1; h[6] = f2c * w1 * w1;
            h[7] = f2c * w0 * w2; h[8] = f2c * w1 * w2;
            h[9]  = f3c * w0 * w0 * w0; h[10] = f3c * w0 * w0 * w1;
            h[11] = f3c * w0 * w1 * w1; h[12] = f3c * w1 * w1 * w1;
        }
#pragma unroll
        for (int c = 0; c < 13; ++c) {
            int m = s * 13 + c;
            int off = m * 512 + ((((j) >> 3) ^ (m & 15)) << 4) + ((j & 7) << 1);
            half_t hA = (half_t)hv[0][c], hB = (half_t)hv[1][c];
            *(hpair*)(smem + J_HI + off) = hpair{hA, hB};
        }
    }
    __syncthreads();

    floatx4 acc[MT][4];

    // ---------------- Layers 2, 3 (each leaves the next kb0 in P0) ----------------
    layer(smem, W2h, b2, wave, lane, vo, q, mx, mr, W3h, P0, acc);
    layer(smem, W3h, b3, wave, lane, vo, q, mx, mr, Wdh, P0, acc);

    // ---------------- Data head (uses J3 comps 0..2); kb0 from P0 (Wd) -------------
    {
        // two head tiles, sample-aligned rows: tile ht row r = 4*sl + c,
        // sample s = ht*4 + sl, comp c (c==3 dummy). Row per lane: r = nl.
        int ch = (nl & 3) == 3 ? 0 : (nl & 3);
        int mh[2];
        mh[0] = (nl >> 2) * 13 + ch;
        {
            int s1 = 4 + (nl >> 2);
            mh[1] = (s1 < TS) ? s1 * 13 + ch : 52;   // clamp (results discarded)
        }
        floatx4 hacc[2][4];
#pragma unroll
        for (int ht = 0; ht < 2; ++ht)
#pragma unroll
            for (int nt = 0; nt < 4; ++nt) hacc[ht][nt] = floatx4{0.f, 0.f, 0.f, 0.f};
        half8 H1[4];
        load_B(Wdh, vo, 1, H1);
        head_phase(smem, mh, 0, q, P0, hacc);   // P0 free
        load_B(Wdh, vo, 2, P0);
        head_phase(smem, mh, 1, q, H1, hacc);
        load_B(Wdh, vo, 3, H1);
        head_phase(smem, mh, 2, q, P0, hacc);
        load_B(Wdh, vo, 4, P0);
        head_phase(smem, mh, 3, q, H1, hacc);
        load_B(Wdh, vo, 5, H1);
        head_phase(smem, mh, 4, q, P0, hacc);
        load_B(Wdh, vo, 6, P0);
        head_phase(smem, mh, 5, q, H1, hacc);
        load_B(Wdh, vo, 7, H1);
        head_phase(smem, mh, 6, q, P0, hacc);   // P0 free
        load_B(Wph, vo, 0, P0);                 // prefetch Wp1 kb0
        head_phase(smem, mh, 7, q, H1, hacc);
        // head epilogue: C row = 4*sl + c -> sample ht*4 + q, comp = reg (0..2 used)
        float* rb = (float*)(smem + REDBUF);
#pragma unroll
        for (int ht = 0; ht < 2; ++ht) {
            float pp = 0, up = 0, vp = 0;
#pragma unroll
            for (int nt = 0; nt < 4; ++nt) {
                int n = wave * 64 + nt * 16 + nl;
                floatx4 a = hacc[ht][nt];
                float f = fast_tanh(a.x + bd1[n]);
                float f1 = 1.f - f * f;
                float hdx = f1 * a.y, hdy = f1 * a.z;
                float w0 = Wd2[n], w1 = Wd2[HID + n];
                pp += w1 * f;
                up += w0 * hdy;
                vp -= w0 * hdx;
            }
#pragma unroll
            for (int msk = 1; msk < 16; msk <<= 1) {
                pp += __shfl_xor(pp, msk, 64);
                up += __shfl_xor(up, msk, 64);
                vp += __shfl_xor(vp, msk, 64);
            }
            int s = ht * 4 + q;
            if (nl == 0 && s < TS) {
                rb[(s * 4 + wave) * 3 + 0] = pp;
                rb[(s * 4 + wave) * 3 + 1] = up;
                rb[(s * 4 + wave) * 3 + 2] = vp;
            }
        }
        __syncthreads();
        if (t < TS && base + t < N_PTS) {
            float P = 0, U = 0, V = 0;
#pragma unroll
            for (int w = 0; w < 4; ++w) {
                P += rb[(t * 4 + w) * 3 + 0];
                U += rb[(t * 4 + w) * 3 + 1];
                V += rb[(t * 4 + w) * 3 + 2];
            }
            out[0 * N_PTS + base + t] = P + bd2[1];
            out[1 * N_PTS + base + t] = U;
            out[2 * N_PTS + base + t] = V;
        }
    }

    // ---------------- PDE-head layer Wp1 (kb0 from P0; dummy next-prefetch) --------
    layer(smem, Wph, bp1, wave, lane, vo, q, mx, mr, Wdh, P0, acc);

    // ---------------- PDE reduction from J4 (vectorized: 16B chunk per lane) -------
    {
        int s = t >> 5, gl = t & 31;
        if (s < TS) {
            // lane gl owns k = gl*8 .. gl*8+7 (one 16 B chunk per row)
            floatx4 w0a = *(const floatx4*)(Wp2 + gl * 8);
            floatx4 w0b = *(const floatx4*)(Wp2 + gl * 8 + 4);
            floatx4 w1a = *(const floatx4*)(Wp2 + HID + gl * 8);
            floatx4 w1b = *(const floatx4*)(Wp2 + HID + gl * 8 + 4);
            float wr0[8] = {w0a.x, w0a.y, w0a.z, w0a.w, w0b.x, w0b.y, w0b.z, w0b.w};
            float wr1[8] = {w1a.x, w1a.y, w1a.z, w1a.w, w1b.x, w1b.y, w1b.z, w1b.w};
            float S[13], px = 0.f, py = 0.f;
#pragma unroll
            for (int c = 0; c < 13; ++c) {
                const int m = s * 13 + c;
                const int off = m * 512 + ((gl ^ (m & 15)) << 4);
                half8 hv = *(const half8*)(smem + J_HI + off);
                float p = 0.f, p2 = 0.f;
#pragma unroll
                for (int e = 0; e < 8; ++e) {
                    float val = (float)hv[e];
                    p += val * wr0[e];
                    if (c == 1 || c == 2) p2 += val * wr1[e];
                }
#pragma unroll
                for (int msk = 1; msk < 32; msk <<= 1) p += __shfl_xor(p, msk, 64);
                S[c] = p;
                if (c == 1) {
#pragma unroll
                    for (int msk = 1; msk < 32; msk <<= 1) p2 += __shfl_xor(p2, msk, 64);
                    px = p2;
                } else if (c == 2) {
#pragma unroll
                    for (int msk = 1; msk < 32; msk <<= 1) p2 += __shfl_xor(p2, msk, 64);
                    py = p2;
                }
            }
            if (gl == 0 && base + s < N_PTS) {
                const float lam1 = lam1p[0], lam2 = lam2p[0];
                const float u_ = S[2], v_ = -S[1];
                const float u_x = S[5], u_y = S[6], u_t = S[8];
                const float v_x = -S[4], v_y = -S[5], v_t = -S[7];
                const float u_xx = S[10], u_yy = S[12];
                const float v_xx = -S[9], v_yy = -S[11];
                const float f_ = lam1 * (u_t + u_ * u_x + v_ * u_y) + px - lam2 * (u_xx + u_yy);
                const float g_ = lam1 * (v_t + u_ * v_x + v_ * v_y) + py - lam2 * (v_xx + v_yy);
                out[3 * N_PTS + base + s] = f_;
                out[4 * N_PTS + base + s] = g_;
            }
        }
    }
}

extern "C" void kernel_launch(void* const* d_in, const int* in_sizes, int n_in,
                              void* d_out, int out_size, void* d_ws, size_t ws_size,
                              hipStream_t stream) {
    const float* x   = (const float*)d_in[0];
    const float* y   = (const float*)d_in[1];
    const float* tt  = (const float*)d_in[2];
    const float* W1  = (const float*)d_in[6];
    const float* b1  = (const float*)d_in[7];
    const float* W2  = (const float*)d_in[8];
    const float* b2  = (const float*)d_in[9];
    const float* W3  = (const float*)d_in[10];
    const float* b3  = (const float*)d_in[11];
    const float* Wp1 = (const float*)d_in[12];
    const float* bp1 = (const float*)d_in[13];
    const float* Wp2 = (const float*)d_in[14];
    const float* Wd1 = (const float*)d_in[16];
    const float* bd1 = (const float*)d_in[17];
    const float* Wd2 = (const float*)d_in[18];
    const float* bd2 = (const float*)d_in[19];
    const float* l1  = (const float*)d_in[20];
    const float* l2  = (const float*)d_in[21];
    float* out = (float*)d_out;
    half_t* wsw = (half_t*)d_ws;   // needs 4 * 256 KB = 1 MB

    prep_w<<<256, 256, 0, stream>>>(W2, W3, Wp1, Wd1, wsw);

    (void)hipFuncSetAttribute((const void*)pinn_mfma,
                              hipFuncAttributeMaxDynamicSharedMemorySize,
                              (int)LDS_BYTES);
    pinn_mfma<<<(N_PTS + TS - 1) / TS, 256, LDS_BYTES, stream>>>(
        x, y, tt, W1, b1, b2, b3, bp1, Wp2, bd1, Wd2, bd2, l1, l2, wsw, out);
}

// Round 15
// 603.862 us; speedup vs baseline: 1.0558x; 1.0558x over previous
//
#include <hip/hip_runtime.h>

// MFMA pure-FP16 jet-propagation PINN.
// Jet comps: 0:val 1:x 2:y 3:t 4:xx 5:xy 6:yy 7:xt 8:yt 9:xxx 10:xxy 11:xyy 12:yyy
// J in LDS: PACKED rows m = sample*13 + comp, k = hidden neuron; f16 plane.
// Row layout: 32 chunks of 8 f16 (16 B); phys chunk = logical ^ (m&15)  (bank swizzle).
// R26 (533 us steady, VERIFIED): TS=6 MT=5 at (256,2), VGPR 100, no spill.
// R27/R28 FAILURE LAW: at (256,3) cap 170, acc[5][4]=80 AGPR leaves 90 arch slots;
// allocator pinned arch at 84 -> 34-slot spill -> 380-670 MB scratch, net loss.
// The binding term is the ACCUMULATOR. (R29 = R26 revert; infra failure, never ran.)
// R30: TS=4, MT=4 -> acc 64 AGPR -> 106 arch slots vs ~70-80 demand (kloop 48 B-regs;
// rolling epilogue 32-float window + 26 jet temps). First 3-wave config where the
// registers arithmetically fit. +14.6% MFMA work (81% fill) vs 1.5x depth. LDS 26.8KB.
// Rolling epilogue exact at TS=4 (sample s completes at tile s). Gates: WRITE_SIZE
// <10MB, occupancy ~33. If spill or dur>=533: revert to R26 (256,2), plateau.

#define N_PTS 65536
#define HID   256
#define TS    4
#define MROWS (TS * 13)           // 52 packed rows
#define MT    4                   // M-tiles of 16 rows

typedef _Float16 half_t;
typedef __attribute__((ext_vector_type(8))) _Float16 half8;
typedef __attribute__((ext_vector_type(4))) float floatx4;

#define J_HI   0
#define REDBUF 26624              // 192 B head partials (4 samples * 4 waves * 3)
#define LDS_BYTES (REDBUF + 192)  // 26816 B -> 3+ blocks/CU (LDS not binding)

struct alignas(4) hpair { half_t a, b; };

__device__ __forceinline__ float fast_tanh(float x) {
    float e = __builtin_amdgcn_exp2f(x * 2.885390081777927f);
    return 1.f - 2.f * __builtin_amdgcn_rcpf(e + 1.f);
}

__device__ __forceinline__ void tanh_jet(const float* u, float* h) {
    const float f  = fast_tanh(u[0]);
    const float f1 = 1.f - f * f;
    const float f2 = -2.f * f * f1;
    const float f3 = -2.f * f1 * f1 + 4.f * f * f * f1;
    const float ux = u[1], uy = u[2], ut = u[3];
    const float uxx = u[4], uxy = u[5], uyy = u[6], uxt = u[7], uyt = u[8];
    h[0] = f;
    h[1] = f1 * ux;  h[2] = f1 * uy;  h[3] = f1 * ut;
    h[4] = f2 * ux * ux + f1 * uxx;
    h[5] = f2 * ux * uy + f1 * uxy;
    h[6] = f2 * uy * uy + f1 * uyy;
    h[7] = f2 * ux * ut + f1 * uxt;
    h[8] = f2 * uy * ut + f1 * uyt;
    h[9]  = f3 * ux * ux * ux + 3.f * f2 * ux * uxx + f1 * u[9];
    h[10] = f3 * ux * ux * uy + f2 * (uxx * uy + 2.f * uxy * ux) + f1 * u[10];
    h[11] = f3 * ux * uy * uy + f2 * (uyy * ux + 2.f * uxy * uy) + f1 * u[11];
    h[12] = f3 * uy * uy * uy + 3.f * f2 * uy * uyy + f1 * u[12];
}

// ---- prep: split W2, W3, Wp1, Wd1 into f16 hi/lo planes, FRAGMENT-ORDERED ----
// (lo plane unused by the main kernel; kept for layout compatibility)
// (n,k) -> addr = ((ntile*8 + kb)*64 + q*16 + nl)*8 + e  -> wave loads 1 KB contiguous
__global__ void prep_w(const float* __restrict__ W2, const float* __restrict__ W3,
                       const float* __restrict__ Wp1, const float* __restrict__ Wd1,
                       half_t* __restrict__ ws) {
    int idx = blockIdx.x * 256 + threadIdx.x;
#pragma unroll
    for (int r = 0; r < 4; ++r) {
        int e = idx + r * 65536;
        int m = e >> 16, i = e & 65535;
        const float* src = (m == 0) ? W2 : (m == 1) ? W3 : (m == 2) ? Wp1 : Wd1;
        float w = src[i];
        half_t hi = (half_t)w;
        half_t lo = (half_t)(w - (float)hi);
        int n = i >> 8, k = i & 255;
        int addr = (((n >> 4) * 8 + (k >> 5)) * 64 + ((k >> 3) & 3) * 16 + (n & 15)) * 8
                   + (k & 7);
        ws[m * 131072 + addr] = hi;
        ws[m * 131072 + 65536 + addr] = lo;
    }
}

// coalesced fragment load, SCALAR base: bh is wave-uniform (readfirstlane),
// vo = lane*8 halfs is the only per-lane term -> SGPR-base global_load.
__device__ __forceinline__ void load_B(const half_t* bh, int vo, int kb,
                                       half8 (&Bh)[4]) {
#pragma unroll
    for (int nt = 0; nt < 4; ++nt) {
        int off = nt * 4096 + kb * 512 + vo;   // halfs; nt,kb uniform
        Bh[nt] = *(const half8*)(bh + off);
    }
}

// one kb step: MT A-tiles (precomputed row bases, xor-folded chunk), 16 MFMAs.
__device__ __forceinline__ void mfma_phase(const char* __restrict__ smem,
                                           const int (&mx)[MT], const int (&mr)[MT],
                                           int kb, int q,
                                           const half8 (&Bh)[4],
                                           floatx4 (&acc)[MT][4]) {
    const int kq = (kb * 4 + q) << 4;
    __builtin_amdgcn_s_setprio(1);
#pragma unroll
    for (int mt = 0; mt < MT; ++mt) {
        const int a = mr[mt] + (kq ^ mx[mt]);
        half8 Ah = *(const half8*)(smem + J_HI + a);
#pragma unroll
        for (int nt = 0; nt < 4; ++nt) {
            acc[mt][nt] = __builtin_amdgcn_mfma_f32_16x16x32_f16(Ah, Bh[nt], acc[mt][nt], 0, 0, 0);
        }
    }
    __builtin_amdgcn_s_setprio(0);
}

// ROLLING post-barrier epilogue: per tile, transpose (dual-writeback permlane) into
// ccur[16]; jet sample s = mt (rows 13mt..13mt+12 span cprev|ccur); f16-store to J.
// Peak live: acc (progressively dead) + 32-float window + 26 jet temps.
__device__ __forceinline__ void epilogue_roll(char* __restrict__ smem,
                                              const float* __restrict__ bias,
                                              int wave, int lane,
                                              floatx4 (&acc)[MT][4]) {
    const int n = wave * 64 + lane;
    const float bn = bias[n];
    const int lanebase = ((n >> 3) << 4) | ((n & 7) << 1);
    float cprev[16], ccur[16];
#pragma unroll
    for (int mt = 0; mt < MT; ++mt) {
        float tv[4][4];
#pragma unroll
        for (int j = 0; j < 4; ++j)
#pragma unroll
            for (int r = 0; r < 4; ++r) tv[j][r] = acc[mt][j][r];
#pragma unroll
        for (int r = 0; r < 4; ++r) {
            asm("v_permlane16_swap_b32 %0, %1" : "+v"(tv[0][r]), "+v"(tv[1][r]));
            asm("v_permlane16_swap_b32 %0, %1" : "+v"(tv[2][r]), "+v"(tv[3][r]));
            asm("v_permlane32_swap_b32 %0, %1" : "+v"(tv[0][r]), "+v"(tv[2][r]));
            asm("v_permlane32_swap_b32 %0, %1" : "+v"(tv[1][r]), "+v"(tv[3][r]));
        }
#pragma unroll
        for (int j = 0; j < 4; ++j)
#pragma unroll
            for (int r = 0; r < 4; ++r) ccur[j * 4 + r] = tv[j][r];
        // jet sample s = mt: row 13mt+c lives in tile (row>>4) = mt or mt-1
        float u[13], h[13];
#pragma unroll
        for (int c = 0; c < 13; ++c) {
            const int row = 13 * mt + c;
            u[c] = ((row >> 4) == mt) ? ccur[row & 15] : cprev[row & 15];
        }
        u[0] += bn;
        tanh_jet(u, h);
#pragma unroll
        for (int c = 0; c < 13; ++c) {
            const int m = 13 * mt + c;
            const int off = m * 512 + (lanebase ^ ((m & 15) << 4));
            *(half_t*)(smem + J_HI + off) = (half_t)h[c];
        }
#pragma unroll
        for (int i = 0; i < 16; ++i) cprev[i] = ccur[i];
    }
}

// one full layer: kb0 consumes persistent-prefetched P0; kb1..7 double-buffered;
// next-layer kb0 prefetch issued pre-barrier (register write, no LDS hazard).
__device__ __forceinline__ void layer(char* __restrict__ smem,
                                      const half_t* bh,
                                      const float* __restrict__ bias,
                                      int wave, int lane, int vo, int q, int nl,
                                      const half_t* nbh,
                                      half8 (&P0h)[4],
                                      floatx4 (&acc)[MT][4]) {
    int mx[MT], mr[MT];
#pragma unroll
    for (int mt = 0; mt < MT; ++mt) {
        int m = mt * 16 + nl;
        if (m > MROWS - 1) m = MROWS - 1;   // tile 3 clamp (C rows 52..63 discarded)
        mx[mt] = (m & 15) << 4;
        mr[mt] = m * 512;
    }
    half8 B1h[4], B2h[4];
    load_B(bh, vo, 1, B1h);
#pragma unroll
    for (int mt = 0; mt < MT; ++mt)
#pragma unroll
        for (int nt = 0; nt < 4; ++nt) acc[mt][nt] = floatx4{0.f, 0.f, 0.f, 0.f};
    mfma_phase(smem, mx, mr, 0, q, P0h, acc);
    load_B(bh, vo, 2, B2h);
    mfma_phase(smem, mx, mr, 1, q, B1h, acc);
#pragma unroll 1
    for (int kb = 2; kb < 8; kb += 2) {
        load_B(bh, vo, kb + 1, B1h);
        mfma_phase(smem, mx, mr, kb, q, B2h, acc);
        if (kb + 2 < 8) load_B(bh, vo, kb + 2, B2h);
        mfma_phase(smem, mx, mr, kb + 1, q, B1h, acc);
    }
    load_B(nbh, vo, 0, P0h);         // prefetch next layer kb0 (pre-barrier)
    __syncthreads();                 // all waves' J reads done before overwrite
    epilogue_roll(smem, bias, wave, lane, acc);
    __syncthreads();                 // publish new J
}

// head kb step: 1 tile (16 sample-aligned rows cover all 4 samples), 4 MFMAs
__device__ __forceinline__ void head_phase(const char* __restrict__ smem,
                                           int mrh, int mxh, int kb, int q,
                                           const half8 (&Bh)[4],
                                           floatx4 (&hacc)[4]) {
    __builtin_amdgcn_s_setprio(1);
    const int a = mrh + (((kb * 4 + q) << 4) ^ mxh);
    half8 Ah = *(const half8*)(smem + J_HI + a);
#pragma unroll
    for (int nt = 0; nt < 4; ++nt) {
        hacc[nt] = __builtin_amdgcn_mfma_f32_16x16x32_f16(Ah, Bh[nt], hacc[nt], 0, 0, 0);
    }
    __builtin_amdgcn_s_setprio(0);
}

__global__ __launch_bounds__(256, 3) void pinn_mfma(
    const float* __restrict__ gx, const float* __restrict__ gy, const float* __restrict__ gt,
    const float* __restrict__ W1, const float* __restrict__ b1,
    const float* __restrict__ b2, const float* __restrict__ b3,
    const float* __restrict__ bp1, const float* __restrict__ Wp2,
    const float* __restrict__ bd1, const float* __restrict__ Wd2,
    const float* __restrict__ bd2,
    const float* __restrict__ lam1p, const float* __restrict__ lam2p,
    const half_t* __restrict__ wsw, float* __restrict__ out) {
    extern __shared__ char smem[];
    const int t = threadIdx.x;
    const int wave = t >> 6, lane = t & 63;
    const int q = lane >> 4, nl = lane & 15;
    const int base = blockIdx.x * TS;
    // wave-uniform B base offset (halfs) + per-lane offset: scalarized addressing
    const int wo = __builtin_amdgcn_readfirstlane(wave) * 16384;
    const int vo = lane * 8;

    const half_t* W2h = wsw + wo;
    const half_t* W3h = wsw + 131072 + wo;
    const half_t* Wph = wsw + 2 * 131072 + wo;
    const half_t* Wdh = wsw + 3 * 131072 + wo;

    // persistent kb0 prefetch buffer: W2's kb0 load hides under the prologue
    half8 P0h[4];
    load_B(W2h, vo, 0, P0h);

    // ---------------- Layer 1: (x,y,t) -> J1 ----------------
#pragma unroll 1
    for (int ii = 0; ii < 2; ++ii) {
        int p = ii * 256 + t;               // (sample, j-pair) 0..TS*128-1 (=512 exact)
        int s = p >> 7, j = (p & 127) * 2;
        float qx = gx[base + s], qy = gy[base + s], qt = gt[base + s];
        float hv[2][13];
#pragma unroll
        for (int d = 0; d < 2; ++d) {
            int jj = j + d;
            float w0 = W1[3 * jj], w1 = W1[3 * jj + 1], w2 = W1[3 * jj + 2];
            float f = fast_tanh(w0 * qx + w1 * qy + w2 * qt + b1[jj]);
            float f1 = 1.f - f * f;
            float f2c = -2.f * f * f1;
            float f3c = -2.f * f1 * f1 + 4.f * f * f * f1;
            float* h = hv[d];
            h[0] = f; h[1] = f1 * w0; h[2] = f1 * w1; h[3] = f1 * w2;
            h[4] = f2c * w0 * w0; h[5] = f2c * w0 * w1; h[6] = f2c * w1 * w1;
            h[7] = f2c * w0 * w2; h[8] = f2c * w1 * w2;
            h[9]  = f3c * w0 * w0 * w0; h[10] = f3c * w0 * w0 * w1;
            h[11] = f3c * w0 * w1 * w1; h[12] = f3c * w1 * w1 * w1;
        }
#pragma unroll
        for (int c = 0; c < 13; ++c) {
            int m = s * 13 + c;
            int off = m * 512 + ((((j) >> 3) ^ (m & 15)) << 4) + ((j & 7) << 1);
            half_t hA = (half_t)hv[0][c], hB = (half_t)hv[1][c];
            *(hpair*)(smem + J_HI + off) = hpair{hA, hB};
        }
    }
    __syncthreads();

    floatx4 acc[MT][4];

    // ---------------- Layers 2, 3 (each prefetches the next kb0 into P0) ----------
    layer(smem, W2h, b2, wave, lane, vo, q, nl, W3h, P0h, acc);
    layer(smem, W3h, b3, wave, lane, vo, q, nl, Wdh, P0h, acc);

    // ---------------- Data head (uses J3 comps 0..2); kb0 from P0 (Wd) -------------
    {
        // single tile, sample-aligned rows: row r = nl = 4s + c, all 4 samples valid
        int ch = (nl & 3) == 3 ? 0 : (nl & 3);
        int mh = (nl >> 2) * 13 + ch;
        const int mxh = (mh & 15) << 4, mrh = mh * 512;
        floatx4 hacc[4];
#pragma unroll
        for (int nt = 0; nt < 4; ++nt) hacc[nt] = floatx4{0.f, 0.f, 0.f, 0.f};
        head_phase(smem, mrh, mxh, 0, q, P0h, hacc);
#pragma unroll 1
        for (int kb = 1; kb < 8; ++kb) {
            half8 Bh[4];
            load_B(Wdh, vo, kb, Bh);
            head_phase(smem, mrh, mxh, kb, q, Bh, hacc);
        }
        // prefetch Wp1 kb0 into P0: hides under the head reduce below
        load_B(Wph, vo, 0, P0h);
        // head epilogue: C row = q*4 + reg -> sample s = q, comp c = reg (0..2 used)
        float* rb = (float*)(smem + REDBUF);
        {
            float pp = 0, up = 0, vp = 0;
#pragma unroll
            for (int nt = 0; nt < 4; ++nt) {
                int n = wave * 64 + nt * 16 + nl;
                floatx4 a = hacc[nt];
                float f = fast_tanh(a.x + bd1[n]);
                float f1 = 1.f - f * f;
                float hdx = f1 * a.y, hdy = f1 * a.z;
                float w0 = Wd2[n], w1 = Wd2[HID + n];
                pp += w1 * f;
                up += w0 * hdy;
                vp -= w0 * hdx;
            }
#pragma unroll
            for (int msk = 1; msk < 16; msk <<= 1) {
                pp += __shfl_xor(pp, msk, 64);
                up += __shfl_xor(up, msk, 64);
                vp += __shfl_xor(vp, msk, 64);
            }
            if (nl == 0) {                  // sample s = q (0..3 all valid at TS=4)
                rb[(q * 4 + wave) * 3 + 0] = pp;
                rb[(q * 4 + wave) * 3 + 1] = up;
                rb[(q * 4 + wave) * 3 + 2] = vp;
            }
        }
        __syncthreads();
        if (t < TS) {
            float P = 0, U = 0, V = 0;
#pragma unroll
            for (int w = 0; w < 4; ++w) {
                P += rb[(t * 4 + w) * 3 + 0];
                U += rb[(t * 4 + w) * 3 + 1];
                V += rb[(t * 4 + w) * 3 + 2];
            }
            out[0 * N_PTS + base + t] = P + bd2[1];
            out[1 * N_PTS + base + t] = U;
            out[2 * N_PTS + base + t] = V;
        }
    }

    // ---------------- PDE-head layer Wp1 (kb0 from P0; dummy next-prefetch) --------
    layer(smem, Wph, bp1, wave, lane, vo, q, nl, Wdh, P0h, acc);

    // ---------------- PDE reduction from J4 (vectorized: 16B chunk per lane) -------
    {
        int s = t >> 5, gl = t & 31;
        if (s < TS) {
            // lane gl owns k = gl*8 .. gl*8+7 (one 16 B chunk per row)
            floatx4 w0a = *(const floatx4*)(Wp2 + gl * 8);
            floatx4 w0b = *(const floatx4*)(Wp2 + gl * 8 + 4);
            floatx4 w1a = *(const floatx4*)(Wp2 + HID + gl * 8);
            floatx4 w1b = *(const floatx4*)(Wp2 + HID + gl * 8 + 4);
            float wr0[8] = {w0a.x, w0a.y, w0a.z, w0a.w, w0b.x, w0b.y, w0b.z, w0b.w};
            float wr1[8] = {w1a.x, w1a.y, w1a.z, w1a.w, w1b.x, w1b.y, w1b.z, w1b.w};
            float S[13], px = 0.f, py = 0.f;
#pragma unroll
            for (int c = 0; c < 13; ++c) {
                const int m = s * 13 + c;
                const int off = m * 512 + ((gl ^ (m & 15)) << 4);
                half8 hv = *(const half8*)(smem + J_HI + off);
                float p = 0.f, p2 = 0.f;
#pragma unroll
                for (int e = 0; e < 8; ++e) {
                    float val = (float)hv[e];
                    p += val * wr0[e];
                    if (c == 1 || c == 2) p2 += val * wr1[e];
                }
#pragma unroll
                for (int msk = 1; msk < 32; msk <<= 1) p += __shfl_xor(p, msk, 64);
                S[c] = p;
                if (c == 1) {
#pragma unroll
                    for (int msk = 1; msk < 32; msk <<= 1) p2 += __shfl_xor(p2, msk, 64);
                    px = p2;
                } else if (c == 2) {
#pragma unroll
                    for (int msk = 1; msk < 32; msk <<= 1) p2 += __shfl_xor(p2, msk, 64);
                    py = p2;
                }
            }
            if (gl == 0) {
                const float lam1 = lam1p[0], lam2 = lam2p[0];
                const float u_ = S[2], v_ = -S[1];
                const float u_x = S[5], u_y = S[6], u_t = S[8];
                const float v_x = -S[4], v_y = -S[5], v_t = -S[7];
                const float u_xx = S[10], u_yy = S[12];
                const float v_xx = -S[9], v_yy = -S[11];
                const float f_ = lam1 * (u_t + u_ * u_x + v_ * u_y) + px - lam2 * (u_xx + u_yy);
                const float g_ = lam1 * (v_t + u_ * v_x + v_ * v_y) + py - lam2 * (v_xx + v_yy);
                out[3 * N_PTS + base + s] = f_;
                out[4 * N_PTS + base + s] = g_;
            }
        }
    }
}

extern "C" void kernel_launch(void* const* d_in, const int* in_sizes, int n_in,
                              void* d_out, int out_size, void* d_ws, size_t ws_size,
                              hipStream_t stream) {
    const float* x   = (const float*)d_in[0];
    const float* y   = (const float*)d_in[1];
    const float* tt  = (const float*)d_in[2];
    const float* W1  = (const float*)d_in[6];
    const float* b1  = (const float*)d_in[7];
    const float* W2  = (const float*)d_in[8];
    const float* b2  = (const float*)d_in[9];
    const float* W3  = (const float*)d_in[10];
    const float* b3  = (const float*)d_in[11];
    const float* Wp1 = (const float*)d_in[12];
    const float* bp1 = (const float*)d_in[13];
    const float* Wp2 = (const float*)d_in[14];
    const float* Wd1 = (const float*)d_in[16];
    const float* bd1 = (const float*)d_in[17];
    const float* Wd2 = (const float*)d_in[18];
    const float* bd2 = (const float*)d_in[19];
    const float* l1  = (const float*)d_in[20];
    const float* l2  = (const float*)d_in[21];
    float* out = (float*)d_out;
    half_t* wsw = (half_t*)d_ws;   // needs 4 * 256 KB = 1 MB

    prep_w<<<256, 256, 0, stream>>>(W2, W3, Wp1, Wd1, wsw);

    (void)hipFuncSetAttribute((const void*)pinn_mfma,
                              hipFuncAttributeMaxDynamicSharedMemorySize,
                              (int)LDS_BYTES);
    pinn_mfma<<<N_PTS / TS, 256, LDS_BYTES, stream>>>(
        x, y, tt, W1, b1, b2, b3, bp1, Wp2, bd1, Wd2, bd2, l1, l2, wsw, out);
}

// Round 16
// 554.917 us; speedup vs baseline: 1.1490x; 1.0882x over previous
//
#include <hip/hip_runtime.h>

// MFMA pure-FP16 jet-propagation PINN — FINAL (plateau kernel, R26 structure).
// Jet comps: 0:val 1:x 2:y 3:t 4:xx 5:xy 6:yy 7:xt 8:yt 9:xxx 10:xxy 11:xyy 12:yyy
// J in LDS: PACKED rows m = sample*13 + comp, k = hidden neuron; f16 plane.
// Row layout: 32 chunks of 8 f16 (16 B); phys chunk = logical ^ (m&15)  (bank swizzle).
// Session ladder: 1552 -> 1128 (tile packing, permlane transpose, xor-fold addr)
// -> 780 (drop A-side split correction; absmax unchanged) -> 533 steady (drop B-side
// correction too; absmax STILL 2^-10 = 1 f16 ulp -> corrections were dead weight).
// Closed boxes (measured): depth x duty law — (256,2) 2w x 17% duty = 34% MfmaUtil
// = 533us; (256,3) TS=4 3w x 13% = 39.5% but +14.6% work = 545us (R30, wash);
// (256,3) TS=6 spills (acc 80 AGPR + ~110 arch > 170 cap; 380-670MB scratch, R27/28).
// Scheduling levers all <=+2% (setprio null, P0 prefetch, pre-barrier epi hoist);
// pair ping-pong -27% (compiler won't interleave across unroll-1 loops).
// Structural constraint: 4 barrier-separated M=78 GEMMs/6 samples; duty capped by
// serial {B-latency + 544 MFMA + 18 barrier-drains + 1.5k VALU epi}; depth capped
// by unified acc+VALU register file. No pipe >40%: latency plateau, not roofline.

#define N_PTS 65536
#define HID   256
#define TS    6
#define MROWS (TS * 13)           // 78 packed rows
#define MT    5                   // M-tiles of 16 rows

typedef _Float16 half_t;
typedef __attribute__((ext_vector_type(8))) _Float16 half8;
typedef __attribute__((ext_vector_type(4))) float floatx4;

#define J_HI   0
#define REDBUF 39936              // 288 B head partials (6 samples * 4 waves * 3)
#define LDS_BYTES (REDBUF + 288)  // 40224 B

struct alignas(4) hpair { half_t a, b; };

__device__ __forceinline__ float fast_tanh(float x) {
    float e = __builtin_amdgcn_exp2f(x * 2.885390081777927f);
    return 1.f - 2.f * __builtin_amdgcn_rcpf(e + 1.f);
}

__device__ __forceinline__ void tanh_jet(const float* u, float* h) {
    const float f  = fast_tanh(u[0]);
    const float f1 = 1.f - f * f;
    const float f2 = -2.f * f * f1;
    const float f3 = -2.f * f1 * f1 + 4.f * f * f * f1;
    const float ux = u[1], uy = u[2], ut = u[3];
    const float uxx = u[4], uxy = u[5], uyy = u[6], uxt = u[7], uyt = u[8];
    h[0] = f;
    h[1] = f1 * ux;  h[2] = f1 * uy;  h[3] = f1 * ut;
    h[4] = f2 * ux * ux + f1 * uxx;
    h[5] = f2 * ux * uy + f1 * uxy;
    h[6] = f2 * uy * uy + f1 * uyy;
    h[7] = f2 * ux * ut + f1 * uxt;
    h[8] = f2 * uy * ut + f1 * uyt;
    h[9]  = f3 * ux * ux * ux + 3.f * f2 * ux * uxx + f1 * u[9];
    h[10] = f3 * ux * ux * uy + f2 * (uxx * uy + 2.f * uxy * ux) + f1 * u[10];
    h[11] = f3 * ux * uy * uy + f2 * (uyy * ux + 2.f * uxy * uy) + f1 * u[11];
    h[12] = f3 * uy * uy * uy + 3.f * f2 * uy * uyy + f1 * u[12];
}

// ---- prep: split W2, W3, Wp1, Wd1 into f16 hi/lo planes, FRAGMENT-ORDERED ----
// (lo plane unused by the main kernel; kept for layout compatibility)
// (n,k) -> addr = ((ntile*8 + kb)*64 + q*16 + nl)*8 + e  -> wave loads 1 KB contiguous
__global__ void prep_w(const float* __restrict__ W2, const float* __restrict__ W3,
                       const float* __restrict__ Wp1, const float* __restrict__ Wd1,
                       half_t* __restrict__ ws) {
    int idx = blockIdx.x * 256 + threadIdx.x;
#pragma unroll
    for (int r = 0; r < 4; ++r) {
        int e = idx + r * 65536;
        int m = e >> 16, i = e & 65535;
        const float* src = (m == 0) ? W2 : (m == 1) ? W3 : (m == 2) ? Wp1 : Wd1;
        float w = src[i];
        half_t hi = (half_t)w;
        half_t lo = (half_t)(w - (float)hi);
        int n = i >> 8, k = i & 255;
        int addr = (((n >> 4) * 8 + (k >> 5)) * 64 + ((k >> 3) & 3) * 16 + (n & 15)) * 8
                   + (k & 7);
        ws[m * 131072 + addr] = hi;
        ws[m * 131072 + 65536 + addr] = lo;
    }
}

// coalesced fragment load, SCALAR base: bh is wave-uniform (readfirstlane),
// vo = lane*8 halfs is the only per-lane term -> SGPR-base global_load.
__device__ __forceinline__ void load_B(const half_t* bh, int vo, int kb,
                                       half8 (&Bh)[4]) {
#pragma unroll
    for (int nt = 0; nt < 4; ++nt) {
        int off = nt * 4096 + kb * 512 + vo;   // halfs; nt,kb uniform
        Bh[nt] = *(const half8*)(bh + off);
    }
}

// one kb step: MT A-tiles (precomputed row bases, xor-folded chunk), 20 MFMAs.
__device__ __forceinline__ void mfma_phase(const char* __restrict__ smem,
                                           const int (&mx)[MT], const int (&mr)[MT],
                                           int kb, int q,
                                           const half8 (&Bh)[4],
                                           floatx4 (&acc)[MT][4]) {
    const int kq = (kb * 4 + q) << 4;
    __builtin_amdgcn_s_setprio(1);
#pragma unroll
    for (int mt = 0; mt < MT; ++mt) {
        const int a = mr[mt] + (kq ^ mx[mt]);
        half8 Ah = *(const half8*)(smem + J_HI + a);
#pragma unroll
        for (int nt = 0; nt < 4; ++nt) {
            acc[mt][nt] = __builtin_amdgcn_mfma_f32_16x16x32_f16(Ah, Bh[nt], acc[mt][nt], 0, 0, 0);
        }
    }
    __builtin_amdgcn_s_setprio(0);
}

// PRE-BARRIER epilogue: permlane transposes + tanh_jet, register-only (reads acc,
// writes ho[78]). Runs before the barrier -> overlaps the block straggler's MFMA.
__device__ __forceinline__ void epi_pre(const float* __restrict__ bias,
                                        int wave, int lane,
                                        floatx4 (&acc)[MT][4], float (&ho)[MROWS]) {
    const int n = wave * 64 + lane;
    const float bn = bias[n];
    float col[MT * 16];
    // samples fully available after transposing tile mt: {0},{1},{2},{3},{4,5}
    const int s_lo[MT] = {0, 1, 2, 3, 4};
    const int s_hi[MT] = {0, 1, 2, 3, 5};
#pragma unroll
    for (int mt = 0; mt < MT; ++mt) {
        float tv[4][4];
#pragma unroll
        for (int j = 0; j < 4; ++j)
#pragma unroll
            for (int r = 0; r < 4; ++r) tv[j][r] = acc[mt][j][r];
#pragma unroll
        for (int r = 0; r < 4; ++r) {
            asm("v_permlane16_swap_b32 %0, %1" : "+v"(tv[0][r]), "+v"(tv[1][r]));
            asm("v_permlane16_swap_b32 %0, %1" : "+v"(tv[2][r]), "+v"(tv[3][r]));
            asm("v_permlane32_swap_b32 %0, %1" : "+v"(tv[0][r]), "+v"(tv[2][r]));
            asm("v_permlane32_swap_b32 %0, %1" : "+v"(tv[1][r]), "+v"(tv[3][r]));
        }
#pragma unroll
        for (int j = 0; j < 4; ++j)
#pragma unroll
            for (int r = 0; r < 4; ++r) col[mt * 16 + j * 4 + r] = tv[j][r];
#pragma unroll
        for (int s = s_lo[mt]; s <= s_hi[mt]; ++s) {
            float u[13], htmp[13];
#pragma unroll
            for (int c = 0; c < 13; ++c) u[c] = col[s * 13 + c];
            u[0] += bn;
            tanh_jet(u, htmp);
#pragma unroll
            for (int c = 0; c < 13; ++c) ho[s * 13 + c] = htmp[c];
        }
    }
}

// POST-BARRIER epilogue: f16 cast + 78 ds_writes (the only barrier-locked part)
__device__ __forceinline__ void epi_post(char* __restrict__ smem, int wave, int lane,
                                         const float (&ho)[MROWS]) {
    const int n = wave * 64 + lane;
    const int lanebase = ((n >> 3) << 4) | ((n & 7) << 1);
#pragma unroll
    for (int m = 0; m < MROWS; ++m) {
        const int off = m * 512 + (lanebase ^ ((m & 15) << 4));
        *(half_t*)(smem + J_HI + off) = (half_t)ho[m];
    }
}

// one full layer: kb0 consumes persistent-prefetched P0; kb1..7 double-buffered.
// Pre-barrier region: issue next-layer kb0 prefetch into P0, then epi_pre VALU.
__device__ __forceinline__ void layer(char* __restrict__ smem,
                                      const half_t* bh,
                                      const float* __restrict__ bias,
                                      int wave, int lane, int vo, int q, int nl,
                                      const half_t* nbh,
                                      half8 (&P0h)[4],
                                      floatx4 (&acc)[MT][4]) {
    int mx[MT], mr[MT];
#pragma unroll
    for (int mt = 0; mt < MT; ++mt) {
        int m = mt * 16 + nl;
        if (m > MROWS - 1) m = MROWS - 1;   // tile 4 clamp (C rows 78/79 discarded)
        mx[mt] = (m & 15) << 4;
        mr[mt] = m * 512;
    }
    half8 B1h[4], B2h[4];
    load_B(bh, vo, 1, B1h);
#pragma unroll
    for (int mt = 0; mt < MT; ++mt)
#pragma unroll
        for (int nt = 0; nt < 4; ++nt) acc[mt][nt] = floatx4{0.f, 0.f, 0.f, 0.f};
    mfma_phase(smem, mx, mr, 0, q, P0h, acc);
    load_B(bh, vo, 2, B2h);
    mfma_phase(smem, mx, mr, 1, q, B1h, acc);
#pragma unroll 1
    for (int kb = 2; kb < 8; kb += 2) {
        load_B(bh, vo, kb + 1, B1h);
        mfma_phase(smem, mx, mr, kb, q, B2h, acc);
        if (kb + 2 < 8) load_B(bh, vo, kb + 2, B2h);
        mfma_phase(smem, mx, mr, kb + 1, q, B1h, acc);
    }
    // ---- pre-barrier region: prefetch next layer's kb0, then register-only epi ----
    load_B(nbh, vo, 0, P0h);
    float ho[MROWS];
    epi_pre(bias, wave, lane, acc, ho);
    __syncthreads();                 // all waves' J reads done before overwrite
    epi_post(smem, wave, lane, ho);
    __syncthreads();                 // publish new J
}

// head kb step: 2 tiles, 8 MFMAs
__device__ __forceinline__ void head_phase(const char* __restrict__ smem,
                                           const int (&mh)[2], int kb, int q,
                                           const half8 (&Bh)[4],
                                           floatx4 (&hacc)[2][4]) {
    __builtin_amdgcn_s_setprio(1);
#pragma unroll
    for (int ht = 0; ht < 2; ++ht) {
        const int a = mh[ht] * 512 + ((((kb * 4 + q) << 4)) ^ ((mh[ht] & 15) << 4));
        half8 Ah = *(const half8*)(smem + J_HI + a);
#pragma unroll
        for (int nt = 0; nt < 4; ++nt) {
            hacc[ht][nt] = __builtin_amdgcn_mfma_f32_16x16x32_f16(Ah, Bh[nt], hacc[ht][nt], 0, 0, 0);
        }
    }
    __builtin_amdgcn_s_setprio(0);
}

__global__ __launch_bounds__(256, 2) void pinn_mfma(
    const float* __restrict__ gx, const float* __restrict__ gy, const float* __restrict__ gt,
    const float* __restrict__ W1, const float* __restrict__ b1,
    const float* __restrict__ b2, const float* __restrict__ b3,
    const float* __restrict__ bp1, const float* __restrict__ Wp2,
    const float* __restrict__ bd1, const float* __restrict__ Wd2,
    const float* __restrict__ bd2,
    const float* __restrict__ lam1p, const float* __restrict__ lam2p,
    const half_t* __restrict__ wsw, float* __restrict__ out) {
    extern __shared__ char smem[];
    const int t = threadIdx.x;
    const int wave = t >> 6, lane = t & 63;
    const int q = lane >> 4, nl = lane & 15;
    const int base = blockIdx.x * TS;
    // wave-uniform B base offset (halfs) + per-lane offset: scalarized addressing
    const int wo = __builtin_amdgcn_readfirstlane(wave) * 16384;
    const int vo = lane * 8;

    const half_t* W2h = wsw + wo;
    const half_t* W3h = wsw + 131072 + wo;
    const half_t* Wph = wsw + 2 * 131072 + wo;
    const half_t* Wdh = wsw + 3 * 131072 + wo;

    // persistent kb0 prefetch buffer: W2's kb0 load hides under the prologue
    half8 P0h[4];
    load_B(W2h, vo, 0, P0h);

    // ---------------- Layer 1: (x,y,t) -> J1 ----------------
#pragma unroll 1
    for (int ii = 0; ii < 3; ++ii) {
        int p = ii * 256 + t;               // (sample, j-pair) 0..TS*128-1 (=768 exact)
        int s = p >> 7, j = (p & 127) * 2;
        int gi = base + s; if (gi >= N_PTS) gi = N_PTS - 1;   // tail clamp
        float qx = gx[gi], qy = gy[gi], qt = gt[gi];
        float hv[2][13];
#pragma unroll
        for (int d = 0; d < 2; ++d) {
            int jj = j + d;
            float w0 = W1[3 * jj], w1 = W1[3 * jj + 1], w2 = W1[3 * jj + 2];
            float f = fast_tanh(w0 * qx + w1 * qy + w2 * qt + b1[jj]);
            float f1 = 1.f - f * f;
            float f2c = -2.f * f * f1;
            float f3c = -2.f * f1 * f1 + 4.f * f * f * f1;
            float* h = hv[d];
            h[0] = f; h[1] = f1 * w0; h[2] = f1 * w1; h[3] = f1 * w2;
            h[4] = f2c * w0 * w0; h[5] = f2c * w0 * w1; h[6] = f2c * w1 * w1;
            h[7] = f2c * w0 * w2; h[8] = f2c * w1 * w2;
            h[9]  = f3c * w0 * w0 * w0; h[10] = f3c * w0 * w0 * w1;
            h[11] = f3c * w0 * w1 * w1; h[12] = f3c * w1 * w1 * w1;
        }
#pragma unroll
        for (int c = 0; c < 13; ++c) {
            int m = s * 13 + c;
            int off = m * 512 + ((((j) >> 3) ^ (m & 15)) << 4) + ((j & 7) << 1);
            half_t hA = (half_t)hv[0][c], hB = (half_t)hv[1][c];
            *(hpair*)(smem + J_HI + off) = hpair{hA, hB};
        }
    }
    __syncthreads();

    floatx4 acc[MT][4];

    // ---------------- Layers 2, 3 (each prefetches the next kb0 into P0) ----------
    layer(smem, W2h, b2, wave, lane, vo, q, nl, W3h, P0h, acc);
    layer(smem, W3h, b3, wave, lane, vo, q, nl, Wdh, P0h, acc);

    // ---------------- Data head (uses J3 comps 0..2); kb0 from P0 (Wd) -------------
    {
        // two head tiles, sample-aligned rows: tile ht row r = 4*sl + c,
        // sample s = ht*4 + sl, comp c (c==3 dummy). Row per lane: r = nl.
        int ch = (nl & 3) == 3 ? 0 : (nl & 3);
        int mh[2];
        mh[0] = (nl >> 2) * 13 + ch;
        {
            int s1 = 4 + (nl >> 2);
            mh[1] = (s1 < TS) ? s1 * 13 + ch : 52;   // clamp (results discarded)
        }
        floatx4 hacc[2][4];
#pragma unroll
        for (int ht = 0; ht < 2; ++ht)
#pragma unroll
            for (int nt = 0; nt < 4; ++nt) hacc[ht][nt] = floatx4{0.f, 0.f, 0.f, 0.f};
        head_phase(smem, mh, 0, q, P0h, hacc);
#pragma unroll 1
        for (int kb = 1; kb < 8; ++kb) {
            half8 Bh[4];
            load_B(Wdh, vo, kb, Bh);
            head_phase(smem, mh, kb, q, Bh, hacc);
        }
        // prefetch Wp1 kb0 into P0: hides under the head reduce below
        load_B(Wph, vo, 0, P0h);
        // head epilogue: C row = 4*sl + c -> sample ht*4 + q, comp = reg (0..2 used)
        float* rb = (float*)(smem + REDBUF);
#pragma unroll
        for (int ht = 0; ht < 2; ++ht) {
            float pp = 0, up = 0, vp = 0;
#pragma unroll
            for (int nt = 0; nt < 4; ++nt) {
                int n = wave * 64 + nt * 16 + nl;
                floatx4 a = hacc[ht][nt];
                float f = fast_tanh(a.x + bd1[n]);
                float f1 = 1.f - f * f;
                float hdx = f1 * a.y, hdy = f1 * a.z;
                float w0 = Wd2[n], w1 = Wd2[HID + n];
                pp += w1 * f;
                up += w0 * hdy;
                vp -= w0 * hdx;
            }
#pragma unroll
            for (int msk = 1; msk < 16; msk <<= 1) {
                pp += __shfl_xor(pp, msk, 64);
                up += __shfl_xor(up, msk, 64);
                vp += __shfl_xor(vp, msk, 64);
            }
            int s = ht * 4 + q;
            if (nl == 0 && s < TS) {
                rb[(s * 4 + wave) * 3 + 0] = pp;
                rb[(s * 4 + wave) * 3 + 1] = up;
                rb[(s * 4 + wave) * 3 + 2] = vp;
            }
        }
        __syncthreads();
        if (t < TS && base + t < N_PTS) {
            float P = 0, U = 0, V = 0;
#pragma unroll
            for (int w = 0; w < 4; ++w) {
                P += rb[(t * 4 + w) * 3 + 0];
                U += rb[(t * 4 + w) * 3 + 1];
                V += rb[(t * 4 + w) * 3 + 2];
            }
            out[0 * N_PTS + base + t] = P + bd2[1];
            out[1 * N_PTS + base + t] = U;
            out[2 * N_PTS + base + t] = V;
        }
    }

    // ---------------- PDE-head layer Wp1 (kb0 from P0; dummy next-prefetch) --------
    layer(smem, Wph, bp1, wave, lane, vo, q, nl, Wdh, P0h, acc);

    // ---------------- PDE reduction from J4 (vectorized: 16B chunk per lane) -------
    {
        int s = t >> 5, gl = t & 31;
        if (s < TS) {
            // lane gl owns k = gl*8 .. gl*8+7 (one 16 B chunk per row)
            floatx4 w0a = *(const floatx4*)(Wp2 + gl * 8);
            floatx4 w0b = *(const floatx4*)(Wp2 + gl * 8 + 4);
            floatx4 w1a = *(const floatx4*)(Wp2 + HID + gl * 8);
            floatx4 w1b = *(const floatx4*)(Wp2 + HID + gl * 8 + 4);
            float wr0[8] = {w0a.x, w0a.y, w0a.z, w0a.w, w0b.x, w0b.y, w0b.z, w0b.w};
            float wr1[8] = {w1a.x, w1a.y, w1a.z, w1a.w, w1b.x, w1b.y, w1b.z, w1b.w};
            float S[13], px = 0.f, py = 0.f;
#pragma unroll
            for (int c = 0; c < 13; ++c) {
                const int m = s * 13 + c;
                const int off = m * 512 + ((gl ^ (m & 15)) << 4);
                half8 hv = *(const half8*)(smem + J_HI + off);
                float p = 0.f, p2 = 0.f;
#pragma unroll
                for (int e = 0; e < 8; ++e) {
                    float val = (float)hv[e];
                    p += val * wr0[e];
                    if (c == 1 || c == 2) p2 += val * wr1[e];
                }
#pragma unroll
                for (int msk = 1; msk < 32; msk <<= 1) p += __shfl_xor(p, msk, 64);
                S[c] = p;
                if (c == 1) {
#pragma unroll
                    for (int msk = 1; msk < 32; msk <<= 1) p2 += __shfl_xor(p2, msk, 64);
                    px = p2;
                } else if (c == 2) {
#pragma unroll
                    for (int msk = 1; msk < 32; msk <<= 1) p2 += __shfl_xor(p2, msk, 64);
                    py = p2;
                }
            }
            if (gl == 0 && base + s < N_PTS) {
                const float lam1 = lam1p[0], lam2 = lam2p[0];
                const float u_ = S[2], v_ = -S[1];
                const float u_x = S[5], u_y = S[6], u_t = S[8];
                const float v_x = -S[4], v_y = -S[5], v_t = -S[7];
                const float u_xx = S[10], u_yy = S[12];
                const float v_xx = -S[9], v_yy = -S[11];
                const float f_ = lam1 * (u_t + u_ * u_x + v_ * u_y) + px - lam2 * (u_xx + u_yy);
                const float g_ = lam1 * (v_t + u_ * v_x + v_ * v_y) + py - lam2 * (v_xx + v_yy);
                out[3 * N_PTS + base + s] = f_;
                out[4 * N_PTS + base + s] = g_;
            }
        }
    }
}

extern "C" void kernel_launch(void* const* d_in, const int* in_sizes, int n_in,
                              void* d_out, int out_size, void* d_ws, size_t ws_size,
                              hipStream_t stream) {
    const float* x   = (const float*)d_in[0];
    const float* y   = (const float*)d_in[1];
    const float* tt  = (const float*)d_in[2];
    const float* W1  = (const float*)d_in[6];
    const float* b1  = (const float*)d_in[7];
    const float* W2  = (const float*)d_in[8];
    const float* b2  = (const float*)d_in[9];
    const float* W3  = (const float*)d_in[10];
    const float* b3  = (const float*)d_in[11];
    const float* Wp1 = (const float*)d_in[12];
    const float* bp1 = (const float*)d_in[13];
    const float* Wp2 = (const float*)d_in[14];
    const float* Wd1 = (const float*)d_in[16];
    const float* bd1 = (const float*)d_in[17];
    const float* Wd2 = (const float*)d_in[18];
    const float* bd2 = (const float*)d_in[19];
    const float* l1  = (const float*)d_in[20];
    const float* l2  = (const float*)d_in[21];
    float* out = (float*)d_out;
    half_t* wsw = (half_t*)d_ws;   // needs 4 * 256 KB = 1 MB

    prep_w<<<256, 256, 0, stream>>>(W2, W3, Wp1, Wd1, wsw);

    (void)hipFuncSetAttribute((const void*)pinn_mfma,
                              hipFuncAttributeMaxDynamicSharedMemorySize,
                              (int)LDS_BYTES);
    pinn_mfma<<<(N_PTS + TS - 1) / TS, 256, LDS_BYTES, stream>>>(
        x, y, tt, W1, b1, b2, b3, bp1, Wp2, bd1, Wd2, bd2, l1, l2, wsw, out);
}